// Round 14
// baseline (237.604 us; speedup 1.0000x reference)
//
#include <hip/hip_runtime.h>
#include <hip/hip_bf16.h>

typedef __bf16 bf16_t;
typedef __bf16 bf16x8 __attribute__((ext_vector_type(8)));
typedef float floatx4 __attribute__((ext_vector_type(4)));

#define EMBED 512
#define S_LEN 1024
#define NH 8
#define HD 64
#define LDK 1056   // row stride of packed QK buffer (breaks 2KB L2 camping)
#define LDV 1088   // row stride of V^T buffer
#define LTS 76     // LDS tile row stride (16 bank-starts vs 72's 8-way conflict)
#define LPS 70     // P-buffer row stride in u32 (was 68: 8-way read conflict)

#define MFMA16(a, b, c) __builtin_amdgcn_mfma_f32_16x16x32_bf16(a, b, c, 0, 0, 0)

static __device__ __forceinline__ bf16_t f2bf(float f) {
    unsigned int x = __builtin_bit_cast(unsigned int, f);
    unsigned int lsb = (x >> 16) & 1u;
    x += 0x7fffu + lsb;                 // RNE
    unsigned short u = (unsigned short)(x >> 16);
    return __builtin_bit_cast(bf16_t, u);
}
static __device__ __forceinline__ float bf2f(bf16_t v) {
    unsigned short u = __builtin_bit_cast(unsigned short, v);
    unsigned int x = ((unsigned int)u) << 16;
    return __builtin_bit_cast(float, x);
}
// pack two f32 -> one u32 holding two bf16 (truncate; used where values >= 0)
static __device__ __forceinline__ unsigned int pack2(float lo, float hi) {
    return (__builtin_bit_cast(unsigned int, lo) >> 16) |
           (__builtin_bit_cast(unsigned int, hi) & 0xFFFF0000u);
}
// pack two f32 -> u32 of two RNE bf16
static __device__ __forceinline__ unsigned int pack2r(float lo, float hi) {
    unsigned short a = __builtin_bit_cast(unsigned short, f2bf(lo));
    unsigned short b = __builtin_bit_cast(unsigned short, f2bf(hi));
    return (unsigned int)a | ((unsigned int)b << 16);
}
// async 16B global->LDS (linear dest: wave-uniform base + lane*16)
static __device__ __forceinline__ void gload16(const bf16_t* g, bf16_t* l) {
    __builtin_amdgcn_global_load_lds(
        (const __attribute__((address_space(1))) unsigned int*)g,
        (__attribute__((address_space(3))) unsigned int*)l, 16, 0, 0);
}

// ---------------------------------------------------------------------------
// Fused LayerNorm + weight cvt, one launch (R13-measured, neutral-kept).
// ---------------------------------------------------------------------------
__global__ __launch_bounds__(256) void ln_cvt_kernel(const float* __restrict__ x,
                                                     const float* __restrict__ gamma,
                                                     const float* __restrict__ beta,
                                                     bf16_t* __restrict__ xn,
                                                     const float* __restrict__ w0,
                                                     const float* __restrict__ w1,
                                                     const float* __restrict__ w2,
                                                     const float* __restrict__ w3,
                                                     bf16_t* __restrict__ d0,
                                                     bf16_t* __restrict__ d1,
                                                     bf16_t* __restrict__ d2,
                                                     bf16_t* __restrict__ d3) {
    __shared__ float T[16][521];          // [s][c-swizzled], 33.3 KB
    __shared__ float Pm[16][65], Pq[16][65];
    __shared__ float Mu[16], Rs[16];
    int bid = blockIdx.x;
    int t = threadIdx.x;
    if (bid >= 512) {
        // ---- weight cvt: 512 blocks x 2048 elems ----
        int cb2 = bid - 512;
        const float* s; bf16_t* d;
        switch (cb2 >> 7) {
            case 0:  s = w0; d = d0; break;
            case 1:  s = w1; d = d1; break;
            case 2:  s = w2; d = d2; break;
            default: s = w3; d = d3; break;
        }
        int i = ((cb2 & 127) * 256 + t) * 8;
#pragma unroll
        for (int j = 0; j < 8; ++j) d[i + j] = f2bf(s[i + j]);
        return;
    }
    // ---- LN of tile (b, s0..s0+15) ----
    int b = bid >> 6, s0 = (bid & 63) * 16;
    int lc = t >> 2;              // channel row within pass (0..63)
    int si = (t & 3) * 4;         // s offset (0,4,8,12)
    const float* xp = x + ((size_t)b * EMBED + lc) * S_LEN + s0 + si;
    float sm[4] = {}, sq[4] = {};
#pragma unroll
    for (int p = 0; p < 8; ++p) {
        int c = lc + p * 64;
        float4 v = *(const float4*)(xp + (size_t)p * 64 * S_LEN);
        int cs = c ^ ((c >> 3) & 0x38);   // XOR cblk bits into m bits
        T[si + 0][cs] = v.x; T[si + 1][cs] = v.y;
        T[si + 2][cs] = v.z; T[si + 3][cs] = v.w;
        sm[0] += v.x; sq[0] += v.x * v.x;
        sm[1] += v.y; sq[1] += v.y * v.y;
        sm[2] += v.z; sq[2] += v.z * v.z;
        sm[3] += v.w; sq[3] += v.w * v.w;
    }
#pragma unroll
    for (int k = 0; k < 4; ++k) { Pm[si + k][lc] = sm[k]; Pq[si + k][lc] = sq[k]; }
    __syncthreads();
    if (t < 16) {
        float m = 0.f, q = 0.f;
#pragma unroll
        for (int j = 0; j < 64; ++j) { m += Pm[t][j]; q += Pq[t][j]; }
        float mu = m * (1.0f / EMBED);
        float var = q * (1.0f / EMBED) - mu * mu;
        Mu[t] = mu; Rs[t] = rsqrtf(var + 1e-5f);
    }
    __syncthreads();
    int cidx = t & 31;            // 16-c chunk
    int rw = t >> 5;              // 0..7
#pragma unroll
    for (int rg = 0; rg < 2; ++rg) {
        int srl = rg * 8 + rw;
        float mu = Mu[srl], rs = Rs[srl];
        int cb = cidx * 16;
        bf16_t* dst = xn + ((size_t)b * S_LEN + s0 + srl) * EMBED + cb;
#pragma unroll
        for (int h = 0; h < 2; ++h) {
            int c0h = cb + h * 8;
            float4 g0 = *(const float4*)(gamma + c0h);
            float4 g1 = *(const float4*)(gamma + c0h + 4);
            float4 be0 = *(const float4*)(beta + c0h);
            float4 be1 = *(const float4*)(beta + c0h + 4);
            float gv[8] = {g0.x, g0.y, g0.z, g0.w, g1.x, g1.y, g1.z, g1.w};
            float bv[8] = {be0.x, be0.y, be0.z, be0.w, be1.x, be1.y, be1.z, be1.w};
            bf16x8 o;
#pragma unroll
            for (int j = 0; j < 8; ++j) {
                int c = c0h + j;
                int cs = c ^ ((c >> 3) & 0x38);
                o[j] = f2bf((T[srl][cs] - mu) * rs * gv[j] + bv[j]);
            }
            *(bf16x8*)(dst + h * 8) = o;
        }
    }
}

// ---------------------------------------------------------------------------
// Act-stationary GEMM, 128x128 tile: packed QKV projection (R9-verified).
// ---------------------------------------------------------------------------
__global__ __launch_bounds__(256) void gemm_kernel(const bf16_t* __restrict__ X,
                                                   const bf16_t* __restrict__ W,
                                                   const float* __restrict__ b0,
                                                   const float* __restrict__ b1,
                                                   const float* __restrict__ b2,
                                                   bf16_t* __restrict__ Y,
                                                   bf16_t* __restrict__ vtb) {
    __shared__ __align__(16) bf16_t Sh[2][128 * 72];     // 36.9 KB; [0,32KB)=2 linear W bufs
    bf16_t* Wlin = &Sh[0][0];
    int t = threadIdx.x;
    int col0 = blockIdx.y * 128, row0 = blockIdx.x * 128;
    int lane = t & 63, w = t >> 6, g = lane >> 4, n16 = lane & 15;
    int swzk = (((lane & 7) ^ (lane >> 3)) & 7) * 8;     // element offset in 64
    const bf16_t* wg = W + (size_t)(col0 + w * 32 + (lane >> 3)) * EMBED + swzk;
    bf16_t* ldwave = Wlin + (w * 4) * 512;               // + j*512 (+ buf*8192)
    {   // preload chunk 0 (k = 0..63)
#pragma unroll
        for (int j = 0; j < 4; ++j)
            gload16(wg + (size_t)j * 8 * EMBED, ldwave + j * 512);
    }
    int rw0 = row0 + w * 32;
    const bf16_t* xr0 = X + (size_t)(rw0 + n16) * EMBED + g * 8;
    const bf16_t* xr1 = xr0 + (size_t)16 * EMBED;
    bf16x8 a00 = *(const bf16x8*)(xr0);
    bf16x8 a01 = *(const bf16x8*)(xr0 + 32);
    bf16x8 a10 = *(const bf16x8*)(xr1);
    bf16x8 a11 = *(const bf16x8*)(xr1 + 32);
    __syncthreads();
    floatx4 acc[2][8] = {};
    int cs0 = ((g ^ (n16 & 7))) * 8;                     // kk=0 swizzled col; kk=1 = cs0^32
#pragma unroll
    for (int kc = 0; kc < 8; ++kc) {
        bf16x8 na00, na01, na10, na11;
        if (kc < 7) {
            int ko = (kc + 1) * 64;
            bf16_t* ld = Wlin + ((kc + 1) & 1) * 8192 + (w * 4) * 512;
#pragma unroll
            for (int j = 0; j < 4; ++j)
                gload16(wg + (size_t)j * 8 * EMBED + ko, ld + j * 512);
            na00 = *(const bf16x8*)(xr0 + ko);
            na01 = *(const bf16x8*)(xr0 + ko + 32);
            na10 = *(const bf16x8*)(xr1 + ko);
            na11 = *(const bf16x8*)(xr1 + ko + 32);
        }
        const bf16_t* wb = Wlin + (kc & 1) * 8192;
#pragma unroll
        for (int kk = 0; kk < 2; ++kk) {
            bf16x8 s0 = (kk == 0) ? a00 : a01;
            bf16x8 s1 = (kk == 0) ? a10 : a11;
            int csk = cs0 ^ (kk * 32);
#pragma unroll
            for (int nt = 0; nt < 8; ++nt) {
                bf16x8 bfr = *(const bf16x8*)(&wb[(nt * 16 + n16) * 64 + csk]);
                acc[0][nt] = MFMA16(s0, bfr, acc[0][nt]);
                acc[1][nt] = MFMA16(s1, bfr, acc[1][nt]);
            }
        }
        if (kc < 7) {
            a00 = na00; a01 = na01; a10 = na10; a11 = na11;
        }
        __syncthreads();   // drains gload_lds (vmcnt) + orders buffer reuse
    }
    if (col0 < 1024) {
        // ---- QK epilogue: natural [token][col] write ----
        const float* bp = (col0 < 512) ? b0 : b1;
#pragma unroll
        for (int ar = 0; ar < 2; ++ar)
#pragma unroll
            for (int nt = 0; nt < 8; ++nt) {
                int col = col0 + nt * 16 + n16;
                float bv = bp[col & 511];
#pragma unroll
                for (int r = 0; r < 4; ++r) {
                    int row = rw0 + ar * 16 + g * 4 + r;
                    Y[(size_t)row * LDK + col] = f2bf(acc[ar][nt][r] + bv);
                }
            }
    } else {
        // ---- V epilogue: transpose via LDS -> vtb[b][channel][token] ----
        bf16_t* Tl = Wlin;                // 128 ch x 136 tok aliases Sh
#pragma unroll
        for (int ar = 0; ar < 2; ++ar)
#pragma unroll
            for (int nt = 0; nt < 8; ++nt) {
                int chl = nt * 16 + n16;
                float bv = b2[(col0 & 511) + chl];
                uint2 pr;
                pr.x = pack2r(acc[ar][nt][0] + bv, acc[ar][nt][1] + bv);
                pr.y = pack2r(acc[ar][nt][2] + bv, acc[ar][nt][3] + bv);
                *(uint2*)(&Tl[chl * 136 + w * 32 + ar * 16 + g * 4]) = pr;
            }
        __syncthreads();
        int ch = t >> 1, seg = (t & 1) * 64;
        int bb = row0 >> 10, s0 = row0 & 1023;
        bf16_t* dst = vtb + ((size_t)(bb * EMBED + (col0 - 1024) + ch)) * LDV + s0 + seg;
        const bf16_t* srcl = &Tl[ch * 136 + seg];
#pragma unroll
        for (int i = 0; i < 8; ++i)
            *(bf16x8*)(dst + i * 8) = *(const bf16x8*)(srcl + i * 8);
    }
}

// ---------------------------------------------------------------------------
// Weight-stationary GEMM, O-projection + bias + residual, NCHW f32 output.
// Al stride 72 -> 76: fragment reads had only 8 distinct bank-starts (8-way
// conflict); 76 gives 16 starts (bank = (6*n16+4g+16kk) mod 32).
// ---------------------------------------------------------------------------
__global__ __launch_bounds__(256) void wsgemm_out_kernel(const bf16_t* __restrict__ Wb,
                                                         const bf16_t* __restrict__ act,
                                                         const float* __restrict__ bias,
                                                         const float* __restrict__ xres,
                                                         float* __restrict__ out) {
    __shared__ __align__(16) bf16_t Al[2][64 * LTS];
    int b = blockIdx.z, n0 = blockIdx.x * 64, m0 = blockIdx.y * 128;
    int t = threadIdx.x;
    int srow = t >> 2, sseg = (t & 3) * 16;
    const bf16_t* asrc = act + ((size_t)b * S_LEN + n0 + srow) * EMBED + sseg;
    {
        bf16x8 r0 = *(const bf16x8*)(asrc);
        bf16x8 r1 = *(const bf16x8*)(asrc + 8);
        bf16_t* d = &Al[0][srow * LTS + sseg];
        *(bf16x8*)d = r0; *(bf16x8*)(d + 8) = r1;
    }
    int lane = t & 63, w = t >> 6, g = lane >> 4, n16 = lane & 15;
    int mw = m0 + w * 32;
    const bf16_t* wr0 = Wb + (size_t)(mw + n16) * EMBED + g * 8;
    const bf16_t* wr1 = wr0 + (size_t)16 * EMBED;
    bf16x8 a00 = *(const bf16x8*)(wr0);
    bf16x8 a01 = *(const bf16x8*)(wr0 + 32);
    bf16x8 a10 = *(const bf16x8*)(wr1);
    bf16x8 a11 = *(const bf16x8*)(wr1 + 32);
    __syncthreads();
    floatx4 acc[2][4] = {};
#pragma unroll
    for (int kc = 0; kc < 8; ++kc) {
        bf16x8 p0, p1, na00, na01, na10, na11;
        if (kc < 7) {
            int ko = (kc + 1) * 64;
            p0 = *(const bf16x8*)(asrc + ko);
            p1 = *(const bf16x8*)(asrc + ko + 8);
            na00 = *(const bf16x8*)(wr0 + ko);
            na01 = *(const bf16x8*)(wr0 + ko + 32);
            na10 = *(const bf16x8*)(wr1 + ko);
            na11 = *(const bf16x8*)(wr1 + ko + 32);
        }
        const bf16_t* al = &Al[kc & 1][0];
#pragma unroll
        for (int kk = 0; kk < 2; ++kk) {
            bf16x8 s0 = (kk == 0) ? a00 : a01;
            bf16x8 s1 = (kk == 0) ? a10 : a11;
#pragma unroll
            for (int nt = 0; nt < 4; ++nt) {
                bf16x8 bfr = *(const bf16x8*)(&al[(nt * 16 + n16) * LTS + kk * 32 + g * 8]);
                acc[0][nt] = MFMA16(s0, bfr, acc[0][nt]);
                acc[1][nt] = MFMA16(s1, bfr, acc[1][nt]);
            }
        }
        if (kc < 7) {
            bf16_t* d = &Al[(kc + 1) & 1][srow * LTS + sseg];
            *(bf16x8*)d = p0; *(bf16x8*)(d + 8) = p1;
            a00 = na00; a01 = na01; a10 = na10; a11 = na11;
        }
        __syncthreads();
    }
#pragma unroll
    for (int ar = 0; ar < 2; ++ar)
#pragma unroll
        for (int r = 0; r < 4; ++r) {
            int row = mw + ar * 16 + g * 4 + r;
            float bv = bias[row];
#pragma unroll
            for (int nt = 0; nt < 4; ++nt) {
                int col = n0 + nt * 16 + n16;
                size_t oi = ((size_t)b * EMBED + row) * S_LEN + col;
                out[oi] = acc[ar][nt][r] + bv + xres[oi];
            }
        }
}

// ---------------------------------------------------------------------------
// Flash attention — R6 structure with bank-conflict-fixed LDS strides:
// K/V tiles 72 -> 76 (fragment reads: 8 bank-starts -> 16; was the source of
// the 3.67M SQ_LDS_BANK_CONFLICT, on the serial path at 2 waves/SIMD);
// P buffer 68 -> 70 u32 (same fix for the uint4 P reads).
// ---------------------------------------------------------------------------
__global__ __launch_bounds__(256) void attn_kernel(const bf16_t* __restrict__ qk,
                                                   const bf16_t* __restrict__ vt,
                                                   bf16_t* __restrict__ o) {
    __shared__ __align__(16) bf16_t Kt[2][64 * LTS];          // 19.0 KB
    __shared__ __align__(16) bf16_t Vl2[2][64 * LTS];         // 19.0 KB
    __shared__ __align__(16) unsigned int Pl[4][16 * LPS];    // 17.5 KB
    int bid = blockIdx.x;
    int bh = bid & 63, qt = bid >> 6;           // qt 0..7
    int b = bh >> 3, h = bh & 7;
    int t = threadIdx.x, w = t >> 6, lane = t & 63, g = lane >> 4, n16 = lane & 15;
    size_t baseQK = (size_t)b * S_LEN * LDK;
    size_t baseV  = ((size_t)b * EMBED + h * HD) * LDV;
    int qA = qt * 128 + w * 32 + n16;

    // Q fragments for both 16-q halves, pre-scaled by (1/sqrt(64))*log2(e)
    const float QSC = 0.18033688f;              // 0.125 * 1.4426950408
    const bf16_t* qpA = qk + baseQK + (size_t)qA * LDK + h * HD + g * 8;
    const bf16_t* qpB = qpA + (size_t)16 * LDK;
    bf16x8 qa0 = *(const bf16x8*)(qpA);
    bf16x8 qa1 = *(const bf16x8*)(qpA + 32);
    bf16x8 qb0 = *(const bf16x8*)(qpB);
    bf16x8 qb1 = *(const bf16x8*)(qpB + 32);
#pragma unroll
    for (int j = 0; j < 8; ++j) {
        qa0[j] = f2bf(bf2f(qa0[j]) * QSC);
        qa1[j] = f2bf(bf2f(qa1[j]) * QSC);
        qb0[j] = f2bf(bf2f(qb0[j]) * QSC);
        qb1[j] = f2bf(bf2f(qb1[j]) * QSC);
    }
    const bf16_t* kbase = qk + baseQK + 512 + h * HD;
    const bf16_t* vbase = vt + baseV;

    // cooperative staging: thread t -> row t>>2 (0..63), 16 elems at (t&3)*16
    int srow = t >> 2, scol = (t & 3) * 16;
    const bf16_t* ksrc = kbase + (size_t)srow * LDK + scol;
    const bf16_t* vsrc = vbase + (size_t)srow * LDV + scol;
    {   // preload tile 0
        bf16x8 k0 = *(const bf16x8*)(ksrc);
        bf16x8 k1 = *(const bf16x8*)(ksrc + 8);
        bf16x8 v0 = *(const bf16x8*)(vsrc);
        bf16x8 v1 = *(const bf16x8*)(vsrc + 8);
        bf16_t* kd = &Kt[0][srow * LTS + scol];
        bf16_t* vd = &Vl2[0][srow * LTS + scol];
        *(bf16x8*)kd = k0; *(bf16x8*)(kd + 8) = k1;
        *(bf16x8*)vd = v0; *(bf16x8*)(vd + 8) = v1;
    }

    float lsA[4] = {}, lsB[4] = {};
    floatx4 oaccA[4] = {}, oaccB[4] = {};
    unsigned int* PLw = &Pl[w][0];
    const float NEG12L2E = -17.3123405f;        // -12 * log2(e)

    for (int it = 0; it < 16; ++it) {
        int cur = it & 1, nxt = cur ^ 1;
        __syncthreads();
        // ---- issue next-tile prefetch (waited at STAGE below, covered) ----
        bf16x8 pk0, pk1, pv0, pv1;
        if (it < 15) {
            const bf16_t* kp = ksrc + (size_t)(it + 1) * 64 * LDK;
            pk0 = *(const bf16x8*)(kp);
            pk1 = *(const bf16x8*)(kp + 8);
            const bf16_t* vp = vsrc + (it + 1) * 64;
            pv0 = *(const bf16x8*)(vp);
            pv1 = *(const bf16x8*)(vp + 8);
        }
        const bf16_t* Kl = &Kt[cur][0];
        const bf16_t* Vl = &Vl2[cur][0];
        // ---- S^T = K Q^T (pre-scaled) + offset for both q-halves ----
        floatx4 sA[4], sB[4];
#pragma unroll
        for (int kb = 0; kb < 4; ++kb) {
            bf16x8 k0 = *(const bf16x8*)(&Kl[(kb * 16 + n16) * LTS + g * 8]);
            bf16x8 k1 = *(const bf16x8*)(&Kl[(kb * 16 + n16) * LTS + 32 + g * 8]);
            sA[kb] = floatx4{NEG12L2E, NEG12L2E, NEG12L2E, NEG12L2E};
            sA[kb] = MFMA16(k0, qa0, sA[kb]);
            sA[kb] = MFMA16(k1, qa1, sA[kb]);
            sB[kb] = floatx4{NEG12L2E, NEG12L2E, NEG12L2E, NEG12L2E};
            sB[kb] = MFMA16(k0, qb0, sB[kb]);
            sB[kb] = MFMA16(k1, qb1, sB[kb]);
        }
        // ---- p = exp2(s); per-lane l partials (no clamp: |s|<~2 here) ----
#pragma unroll
        for (int kb = 0; kb < 4; ++kb)
#pragma unroll
            for (int r = 0; r < 4; ++r) {
                float eA = exp2f(sA[kb][r]);
                sA[kb][r] = eA; lsA[kb] += eA;
                float eB = exp2f(sB[kb][r]);
                sB[kb][r] = eB; lsB[kb] += eB;
            }
        // ---- P^T both halves -> disjoint per-wave LDS regions ----
#pragma unroll
        for (int kb = 0; kb < 4; ++kb) {
            uint2 prA, prB;
            prA.x = pack2(sA[kb][0], sA[kb][1]);
            prA.y = pack2(sA[kb][2], sA[kb][3]);
            *(uint2*)&PLw[n16 * LPS + kb * 8 + g * 2] = prA;
            prB.x = pack2(sB[kb][0], sB[kb][1]);
            prB.y = pack2(sB[kb][2], sB[kb][3]);
            *(uint2*)&PLw[n16 * LPS + 32 + kb * 8 + g * 2] = prB;
        }
        // ---- single store-forward wait, then read both halves ----
        uint4 uA0 = *(const uint4*)&PLw[n16 * LPS + g * 4];
        uint4 uA1 = *(const uint4*)&PLw[n16 * LPS + 16 + g * 4];
        uint4 uB0 = *(const uint4*)&PLw[n16 * LPS + 32 + g * 4];
        uint4 uB1 = *(const uint4*)&PLw[n16 * LPS + 48 + g * 4];
        bf16x8 pfA0 = __builtin_bit_cast(bf16x8, uA0);
        bf16x8 pfA1 = __builtin_bit_cast(bf16x8, uA1);
        bf16x8 pfB0 = __builtin_bit_cast(bf16x8, uB0);
        bf16x8 pfB1 = __builtin_bit_cast(bf16x8, uB1);
        // ---- STAGE next tile to LDS[nxt] (T14: vmcnt wait lands here,
        //      covered; ds_write latency covered by PV MFMAs below) ----
        if (it < 15) {
            bf16_t* kd = &Kt[nxt][srow * LTS + scol];
            bf16_t* vd = &Vl2[nxt][srow * LTS + scol];
            *(bf16x8*)kd = pk0; *(bf16x8*)(kd + 8) = pk1;
            *(bf16x8*)vd = pv0; *(bf16x8*)(vd + 8) = pv1;
        }
        // ---- O^T += V^T P^T (V frags shared across halves) ----
#pragma unroll
        for (int dt = 0; dt < 4; ++dt) {
            bf16x8 v0 = *(const bf16x8*)(&Vl[(dt * 16 + n16) * LTS + g * 8]);
            bf16x8 v1 = *(const bf16x8*)(&Vl[(dt * 16 + n16) * LTS + 32 + g * 8]);
            oaccA[dt] = MFMA16(v0, pfA0, oaccA[dt]);
            oaccA[dt] = MFMA16(v1, pfA1, oaccA[dt]);
            oaccB[dt] = MFMA16(v0, pfB0, oaccB[dt]);
            oaccB[dt] = MFMA16(v1, pfB1, oaccB[dt]);
        }
    }
    // ---- l reductions (once) + epilogue for both halves ----
    float lA = (lsA[0] + lsA[1]) + (lsA[2] + lsA[3]);
    lA += __shfl_xor(lA, 16);
    lA += __shfl_xor(lA, 32);
    float lB = (lsB[0] + lsB[1]) + (lsB[2] + lsB[3]);
    lB += __shfl_xor(lB, 16);
    lB += __shfl_xor(lB, 32);
    float rlA = 1.0f / lA, rlB = 1.0f / lB;
    size_t orowA = ((size_t)b * S_LEN + qA) * EMBED + h * HD;
    size_t orowB = orowA + (size_t)16 * EMBED;
#pragma unroll
    for (int dt = 0; dt < 4; ++dt) {
        uint2 prA, prB;
        prA.x = pack2(oaccA[dt][0] * rlA, oaccA[dt][1] * rlA);
        prA.y = pack2(oaccA[dt][2] * rlA, oaccA[dt][3] * rlA);
        *(uint2*)(o + orowA + dt * 16 + g * 4) = prA;
        prB.x = pack2(oaccB[dt][0] * rlB, oaccB[dt][1] * rlB);
        prB.y = pack2(oaccB[dt][2] * rlB, oaccB[dt][3] * rlB);
        *(uint2*)(o + orowB + dt * 16 + g * 4) = prB;
    }
}

extern "C" void kernel_launch(void* const* d_in, const int* in_sizes, int n_in,
                              void* d_out, int out_size, void* d_ws, size_t ws_size,
                              hipStream_t stream) {
    const float* x     = (const float*)d_in[0];
    const float* Wq    = (const float*)d_in[1];
    const float* bq    = (const float*)d_in[2];
    const float* Wk    = (const float*)d_in[3];
    const float* bk    = (const float*)d_in[4];
    const float* Wv    = (const float*)d_in[5];
    const float* bv    = (const float*)d_in[6];
    const float* Wo    = (const float*)d_in[7];
    const float* bo    = (const float*)d_in[8];
    const float* gamma = (const float*)d_in[9];
    const float* beta  = (const float*)d_in[10];
    float* out = (float*)d_out;

    char* ws = (char*)d_ws;                        // ~27.8 MB used
    bf16_t* xn    = (bf16_t*)ws;                   // [0,8M); reused as attn-out
    bf16_t* qkb   = (bf16_t*)(ws + 8388608);       // packed QK [8192][1056] (17.3 MB)
    bf16_t* wqkv  = (bf16_t*)(ws + 25690112);      // 1.5 MB packed [1536][512]
    bf16_t* wo    = (bf16_t*)(ws + 27262976);      // 512 KB
    bf16_t* ab    = xn;

    // vtb (8.9 MB) lives in d_out: dead before wsgemm_out writes out
    bf16_t* vtb = (bf16_t*)d_out;

    ln_cvt_kernel<<<dim3(1024), 256, 0, stream>>>(x, gamma, beta, xn,
                                                  Wq, Wk, Wv, Wo,
                                                  wqkv, wqkv + 262144,
                                                  wqkv + 524288, wo);
    gemm_kernel<<<dim3(64, 12), 256, 0, stream>>>(xn, wqkv, bq, bk, bv, qkb, vtb);
    attn_kernel<<<dim3(512), 256, 0, stream>>>(qkb, vtb, ab);
    wsgemm_out_kernel<<<dim3(16, 4, 8), 256, 0, stream>>>(wo, ab, bo, x, out);
}

// Round 19
// 169.032 us; speedup vs baseline: 1.4057x; 1.4057x over previous
//
#include <hip/hip_runtime.h>
#include <hip/hip_bf16.h>

typedef __bf16 bf16_t;
typedef __bf16 bf16x8 __attribute__((ext_vector_type(8)));
typedef float floatx4 __attribute__((ext_vector_type(4)));

#define EMBED 512
#define S_LEN 1024
#define NH 8
#define HD 64
#define LDK 1056   // row stride of packed QK buffer (breaks 2KB L2 camping)
#define LDV 1088   // row stride of V^T buffer

#define MFMA16(a, b, c) __builtin_amdgcn_mfma_f32_16x16x32_bf16(a, b, c, 0, 0, 0)

static __device__ __forceinline__ bf16_t f2bf(float f) {
    unsigned int x = __builtin_bit_cast(unsigned int, f);
    unsigned int lsb = (x >> 16) & 1u;
    x += 0x7fffu + lsb;                 // RNE
    unsigned short u = (unsigned short)(x >> 16);
    return __builtin_bit_cast(bf16_t, u);
}
static __device__ __forceinline__ float bf2f(bf16_t v) {
    unsigned short u = __builtin_bit_cast(unsigned short, v);
    unsigned int x = ((unsigned int)u) << 16;
    return __builtin_bit_cast(float, x);
}
// pack two f32 -> one u32 holding two bf16 (truncate; used where values >= 0)
static __device__ __forceinline__ unsigned int pack2(float lo, float hi) {
    return (__builtin_bit_cast(unsigned int, lo) >> 16) |
           (__builtin_bit_cast(unsigned int, hi) & 0xFFFF0000u);
}
// pack two f32 -> u32 of two RNE bf16
static __device__ __forceinline__ unsigned int pack2r(float lo, float hi) {
    unsigned short a = __builtin_bit_cast(unsigned short, f2bf(lo));
    unsigned short b = __builtin_bit_cast(unsigned short, f2bf(hi));
    return (unsigned int)a | ((unsigned int)b << 16);
}
// async 16B global->LDS (linear dest: wave-uniform base + lane*16)
static __device__ __forceinline__ void gload16(const bf16_t* g, bf16_t* l) {
    __builtin_amdgcn_global_load_lds(
        (const __attribute__((address_space(1))) unsigned int*)g,
        (__attribute__((address_space(3))) unsigned int*)l, 16, 0, 0);
}

// ---------------------------------------------------------------------------
// Fused LayerNorm + weight cvt, one launch (R13-measured, neutral-kept).
// ---------------------------------------------------------------------------
__global__ __launch_bounds__(256) void ln_cvt_kernel(const float* __restrict__ x,
                                                     const float* __restrict__ gamma,
                                                     const float* __restrict__ beta,
                                                     bf16_t* __restrict__ xn,
                                                     const float* __restrict__ w0,
                                                     const float* __restrict__ w1,
                                                     const float* __restrict__ w2,
                                                     const float* __restrict__ w3,
                                                     bf16_t* __restrict__ d0,
                                                     bf16_t* __restrict__ d1,
                                                     bf16_t* __restrict__ d2,
                                                     bf16_t* __restrict__ d3) {
    __shared__ float T[16][521];          // [s][c-swizzled], 33.3 KB
    __shared__ float Pm[16][65], Pq[16][65];
    __shared__ float Mu[16], Rs[16];
    int bid = blockIdx.x;
    int t = threadIdx.x;
    if (bid >= 512) {
        // ---- weight cvt: 512 blocks x 2048 elems ----
        int cb2 = bid - 512;
        const float* s; bf16_t* d;
        switch (cb2 >> 7) {
            case 0:  s = w0; d = d0; break;
            case 1:  s = w1; d = d1; break;
            case 2:  s = w2; d = d2; break;
            default: s = w3; d = d3; break;
        }
        int i = ((cb2 & 127) * 256 + t) * 8;
#pragma unroll
        for (int j = 0; j < 8; ++j) d[i + j] = f2bf(s[i + j]);
        return;
    }
    // ---- LN of tile (b, s0..s0+15) ----
    int b = bid >> 6, s0 = (bid & 63) * 16;
    int lc = t >> 2;              // channel row within pass (0..63)
    int si = (t & 3) * 4;         // s offset (0,4,8,12)
    const float* xp = x + ((size_t)b * EMBED + lc) * S_LEN + s0 + si;
    float sm[4] = {}, sq[4] = {};
#pragma unroll
    for (int p = 0; p < 8; ++p) {
        int c = lc + p * 64;
        float4 v = *(const float4*)(xp + (size_t)p * 64 * S_LEN);
        int cs = c ^ ((c >> 3) & 0x38);   // XOR cblk bits into m bits
        T[si + 0][cs] = v.x; T[si + 1][cs] = v.y;
        T[si + 2][cs] = v.z; T[si + 3][cs] = v.w;
        sm[0] += v.x; sq[0] += v.x * v.x;
        sm[1] += v.y; sq[1] += v.y * v.y;
        sm[2] += v.z; sq[2] += v.z * v.z;
        sm[3] += v.w; sq[3] += v.w * v.w;
    }
#pragma unroll
    for (int k = 0; k < 4; ++k) { Pm[si + k][lc] = sm[k]; Pq[si + k][lc] = sq[k]; }
    __syncthreads();
    if (t < 16) {
        float m = 0.f, q = 0.f;
#pragma unroll
        for (int j = 0; j < 64; ++j) { m += Pm[t][j]; q += Pq[t][j]; }
        float mu = m * (1.0f / EMBED);
        float var = q * (1.0f / EMBED) - mu * mu;
        Mu[t] = mu; Rs[t] = rsqrtf(var + 1e-5f);
    }
    __syncthreads();
    int cidx = t & 31;            // 16-c chunk
    int rw = t >> 5;              // 0..7
#pragma unroll
    for (int rg = 0; rg < 2; ++rg) {
        int srl = rg * 8 + rw;
        float mu = Mu[srl], rs = Rs[srl];
        int cb = cidx * 16;
        bf16_t* dst = xn + ((size_t)b * S_LEN + s0 + srl) * EMBED + cb;
#pragma unroll
        for (int h = 0; h < 2; ++h) {
            int c0h = cb + h * 8;
            float4 g0 = *(const float4*)(gamma + c0h);
            float4 g1 = *(const float4*)(gamma + c0h + 4);
            float4 be0 = *(const float4*)(beta + c0h);
            float4 be1 = *(const float4*)(beta + c0h + 4);
            float gv[8] = {g0.x, g0.y, g0.z, g0.w, g1.x, g1.y, g1.z, g1.w};
            float bv[8] = {be0.x, be0.y, be0.z, be0.w, be1.x, be1.y, be1.z, be1.w};
            bf16x8 o;
#pragma unroll
            for (int j = 0; j < 8; ++j) {
                int c = c0h + j;
                int cs = c ^ ((c >> 3) & 0x38);
                o[j] = f2bf((T[srl][cs] - mu) * rs * gv[j] + bv[j]);
            }
            *(bf16x8*)(dst + h * 8) = o;
        }
    }
}

// ---------------------------------------------------------------------------
// Act-stationary GEMM, 128x128 tile: packed QKV projection (R9-verified).
// ---------------------------------------------------------------------------
__global__ __launch_bounds__(256) void gemm_kernel(const bf16_t* __restrict__ X,
                                                   const bf16_t* __restrict__ W,
                                                   const float* __restrict__ b0,
                                                   const float* __restrict__ b1,
                                                   const float* __restrict__ b2,
                                                   bf16_t* __restrict__ Y,
                                                   bf16_t* __restrict__ vtb) {
    __shared__ __align__(16) bf16_t Sh[2][128 * 72];     // 36.9 KB; [0,32KB)=2 linear W bufs
    bf16_t* Wlin = &Sh[0][0];
    int t = threadIdx.x;
    int col0 = blockIdx.y * 128, row0 = blockIdx.x * 128;
    int lane = t & 63, w = t >> 6, g = lane >> 4, n16 = lane & 15;
    int swzk = (((lane & 7) ^ (lane >> 3)) & 7) * 8;     // element offset in 64
    const bf16_t* wg = W + (size_t)(col0 + w * 32 + (lane >> 3)) * EMBED + swzk;
    bf16_t* ldwave = Wlin + (w * 4) * 512;               // + j*512 (+ buf*8192)
    {   // preload chunk 0 (k = 0..63)
#pragma unroll
        for (int j = 0; j < 4; ++j)
            gload16(wg + (size_t)j * 8 * EMBED, ldwave + j * 512);
    }
    int rw0 = row0 + w * 32;
    const bf16_t* xr0 = X + (size_t)(rw0 + n16) * EMBED + g * 8;
    const bf16_t* xr1 = xr0 + (size_t)16 * EMBED;
    bf16x8 a00 = *(const bf16x8*)(xr0);
    bf16x8 a01 = *(const bf16x8*)(xr0 + 32);
    bf16x8 a10 = *(const bf16x8*)(xr1);
    bf16x8 a11 = *(const bf16x8*)(xr1 + 32);
    __syncthreads();
    floatx4 acc[2][8] = {};
    int cs0 = ((g ^ (n16 & 7))) * 8;                     // kk=0 swizzled col; kk=1 = cs0^32
#pragma unroll
    for (int kc = 0; kc < 8; ++kc) {
        bf16x8 na00, na01, na10, na11;
        if (kc < 7) {
            int ko = (kc + 1) * 64;
            bf16_t* ld = Wlin + ((kc + 1) & 1) * 8192 + (w * 4) * 512;
#pragma unroll
            for (int j = 0; j < 4; ++j)
                gload16(wg + (size_t)j * 8 * EMBED + ko, ld + j * 512);
            na00 = *(const bf16x8*)(xr0 + ko);
            na01 = *(const bf16x8*)(xr0 + ko + 32);
            na10 = *(const bf16x8*)(xr1 + ko);
            na11 = *(const bf16x8*)(xr1 + ko + 32);
        }
        const bf16_t* wb = Wlin + (kc & 1) * 8192;
#pragma unroll
        for (int kk = 0; kk < 2; ++kk) {
            bf16x8 s0 = (kk == 0) ? a00 : a01;
            bf16x8 s1 = (kk == 0) ? a10 : a11;
            int csk = cs0 ^ (kk * 32);
#pragma unroll
            for (int nt = 0; nt < 8; ++nt) {
                bf16x8 bfr = *(const bf16x8*)(&wb[(nt * 16 + n16) * 64 + csk]);
                acc[0][nt] = MFMA16(s0, bfr, acc[0][nt]);
                acc[1][nt] = MFMA16(s1, bfr, acc[1][nt]);
            }
        }
        if (kc < 7) {
            a00 = na00; a01 = na01; a10 = na10; a11 = na11;
        }
        __syncthreads();   // drains gload_lds (vmcnt) + orders buffer reuse
    }
    if (col0 < 1024) {
        // ---- QK epilogue: natural [token][col] write ----
        const float* bp = (col0 < 512) ? b0 : b1;
#pragma unroll
        for (int ar = 0; ar < 2; ++ar)
#pragma unroll
            for (int nt = 0; nt < 8; ++nt) {
                int col = col0 + nt * 16 + n16;
                float bv = bp[col & 511];
#pragma unroll
                for (int r = 0; r < 4; ++r) {
                    int row = rw0 + ar * 16 + g * 4 + r;
                    Y[(size_t)row * LDK + col] = f2bf(acc[ar][nt][r] + bv);
                }
            }
    } else {
        // ---- V epilogue: transpose via LDS -> vtb[b][channel][token] ----
        bf16_t* Tl = Wlin;                // 128 ch x 136 tok aliases Sh
#pragma unroll
        for (int ar = 0; ar < 2; ++ar)
#pragma unroll
            for (int nt = 0; nt < 8; ++nt) {
                int chl = nt * 16 + n16;
                float bv = b2[(col0 & 511) + chl];
                uint2 pr;
                pr.x = pack2r(acc[ar][nt][0] + bv, acc[ar][nt][1] + bv);
                pr.y = pack2r(acc[ar][nt][2] + bv, acc[ar][nt][3] + bv);
                *(uint2*)(&Tl[chl * 136 + w * 32 + ar * 16 + g * 4]) = pr;
            }
        __syncthreads();
        int ch = t >> 1, seg = (t & 1) * 64;
        int bb = row0 >> 10, s0 = row0 & 1023;
        bf16_t* dst = vtb + ((size_t)(bb * EMBED + (col0 - 1024) + ch)) * LDV + s0 + seg;
        const bf16_t* srcl = &Tl[ch * 136 + seg];
#pragma unroll
        for (int i = 0; i < 8; ++i)
            *(bf16x8*)(dst + i * 8) = *(const bf16x8*)(srcl + i * 8);
    }
}

// ---------------------------------------------------------------------------
// Weight-stationary GEMM, O-projection + bias + residual, NCHW f32 output
// (stride 72 restored: 76 broke b128 16B alignment, R14 regression)
// ---------------------------------------------------------------------------
__global__ __launch_bounds__(256) void wsgemm_out_kernel(const bf16_t* __restrict__ Wb,
                                                         const bf16_t* __restrict__ act,
                                                         const float* __restrict__ bias,
                                                         const float* __restrict__ xres,
                                                         float* __restrict__ out) {
    __shared__ __align__(16) bf16_t Al[2][64 * 72];
    int b = blockIdx.z, n0 = blockIdx.x * 64, m0 = blockIdx.y * 128;
    int t = threadIdx.x;
    int srow = t >> 2, sseg = (t & 3) * 16;
    const bf16_t* asrc = act + ((size_t)b * S_LEN + n0 + srow) * EMBED + sseg;
    {
        bf16x8 r0 = *(const bf16x8*)(asrc);
        bf16x8 r1 = *(const bf16x8*)(asrc + 8);
        bf16_t* d = &Al[0][srow * 72 + sseg];
        *(bf16x8*)d = r0; *(bf16x8*)(d + 8) = r1;
    }
    int lane = t & 63, w = t >> 6, g = lane >> 4, n16 = lane & 15;
    int mw = m0 + w * 32;
    const bf16_t* wr0 = Wb + (size_t)(mw + n16) * EMBED + g * 8;
    const bf16_t* wr1 = wr0 + (size_t)16 * EMBED;
    bf16x8 a00 = *(const bf16x8*)(wr0);
    bf16x8 a01 = *(const bf16x8*)(wr0 + 32);
    bf16x8 a10 = *(const bf16x8*)(wr1);
    bf16x8 a11 = *(const bf16x8*)(wr1 + 32);
    __syncthreads();
    floatx4 acc[2][4] = {};
#pragma unroll
    for (int kc = 0; kc < 8; ++kc) {
        bf16x8 p0, p1, na00, na01, na10, na11;
        if (kc < 7) {
            int ko = (kc + 1) * 64;
            p0 = *(const bf16x8*)(asrc + ko);
            p1 = *(const bf16x8*)(asrc + ko + 8);
            na00 = *(const bf16x8*)(wr0 + ko);
            na01 = *(const bf16x8*)(wr0 + ko + 32);
            na10 = *(const bf16x8*)(wr1 + ko);
            na11 = *(const bf16x8*)(wr1 + ko + 32);
        }
        const bf16_t* al = &Al[kc & 1][0];
#pragma unroll
        for (int kk = 0; kk < 2; ++kk) {
            bf16x8 s0 = (kk == 0) ? a00 : a01;
            bf16x8 s1 = (kk == 0) ? a10 : a11;
#pragma unroll
            for (int nt = 0; nt < 4; ++nt) {
                bf16x8 bfr = *(const bf16x8*)(&al[(nt * 16 + n16) * 72 + kk * 32 + g * 8]);
                acc[0][nt] = MFMA16(s0, bfr, acc[0][nt]);
                acc[1][nt] = MFMA16(s1, bfr, acc[1][nt]);
            }
        }
        if (kc < 7) {
            bf16_t* d = &Al[(kc + 1) & 1][srow * 72 + sseg];
            *(bf16x8*)d = p0; *(bf16x8*)(d + 8) = p1;
            a00 = na00; a01 = na01; a10 = na10; a11 = na11;
        }
        __syncthreads();
    }
#pragma unroll
    for (int ar = 0; ar < 2; ++ar)
#pragma unroll
        for (int r = 0; r < 4; ++r) {
            int row = mw + ar * 16 + g * 4 + r;
            float bv = bias[row];
#pragma unroll
            for (int nt = 0; nt < 4; ++nt) {
                int col = n0 + nt * 16 + n16;
                size_t oi = ((size_t)b * EMBED + row) * S_LEN + col;
                out[oi] = acc[ar][nt][r] + bv + xres[oi];
            }
        }
}

// ---------------------------------------------------------------------------
// Flash attention — R13 structure (strides 72/68 restored) + 2-DEEP register
// prefetch: loads for tile it+2 are issued at iter it, so the vmcnt wait at
// STAGE (tile it+1) has a FULL iteration (~3.3k cy) of cover instead of
// ~400 cy — removes the per-iter exposed HBM/L2 latency that the cycle
// budget says dominates this latency-bound kernel (2 waves/SIMD).
// Slot parity: LDS[0]/regE hold even tiles, LDS[1]/regO hold odd tiles.
// ---------------------------------------------------------------------------
__global__ __launch_bounds__(256) void attn_kernel(const bf16_t* __restrict__ qk,
                                                   const bf16_t* __restrict__ vt,
                                                   bf16_t* __restrict__ o) {
    __shared__ __align__(16) bf16_t Kt[2][64 * 72];           // 18.4 KB
    __shared__ __align__(16) bf16_t Vl2[2][64 * 72];          // 18.4 KB
    __shared__ __align__(16) unsigned int Pl[4][16 * 68];     // 17.4 KB
    int bid = blockIdx.x;
    int bh = bid & 63, qt = bid >> 6;           // qt 0..7
    int b = bh >> 3, h = bh & 7;
    int t = threadIdx.x, w = t >> 6, lane = t & 63, g = lane >> 4, n16 = lane & 15;
    size_t baseQK = (size_t)b * S_LEN * LDK;
    size_t baseV  = ((size_t)b * EMBED + h * HD) * LDV;
    int qA = qt * 128 + w * 32 + n16;

    // Q fragments for both 16-q halves, pre-scaled by (1/sqrt(64))*log2(e)
    const float QSC = 0.18033688f;              // 0.125 * 1.4426950408
    const bf16_t* qpA = qk + baseQK + (size_t)qA * LDK + h * HD + g * 8;
    const bf16_t* qpB = qpA + (size_t)16 * LDK;
    bf16x8 qa0 = *(const bf16x8*)(qpA);
    bf16x8 qa1 = *(const bf16x8*)(qpA + 32);
    bf16x8 qb0 = *(const bf16x8*)(qpB);
    bf16x8 qb1 = *(const bf16x8*)(qpB + 32);
#pragma unroll
    for (int j = 0; j < 8; ++j) {
        qa0[j] = f2bf(bf2f(qa0[j]) * QSC);
        qa1[j] = f2bf(bf2f(qa1[j]) * QSC);
        qb0[j] = f2bf(bf2f(qb0[j]) * QSC);
        qb1[j] = f2bf(bf2f(qb1[j]) * QSC);
    }
    const bf16_t* kbase = qk + baseQK + 512 + h * HD;
    const bf16_t* vbase = vt + baseV;

    // cooperative staging: thread t -> row t>>2 (0..63), 16 elems at (t&3)*16
    int srow = t >> 2, scol = (t & 3) * 16;
    const bf16_t* ksrc = kbase + (size_t)srow * LDK + scol;
    const bf16_t* vsrc = vbase + (size_t)srow * LDV + scol;
    {   // preload tile 0 -> LDS[0]
        bf16x8 k0 = *(const bf16x8*)(ksrc);
        bf16x8 k1 = *(const bf16x8*)(ksrc + 8);
        bf16x8 v0 = *(const bf16x8*)(vsrc);
        bf16x8 v1 = *(const bf16x8*)(vsrc + 8);
        bf16_t* kd = &Kt[0][srow * 72 + scol];
        bf16_t* vd = &Vl2[0][srow * 72 + scol];
        *(bf16x8*)kd = k0; *(bf16x8*)(kd + 8) = k1;
        *(bf16x8*)vd = v0; *(bf16x8*)(vd + 8) = v1;
    }
    // preload tile 1 into odd-slot regs
    bf16x8 rkO0, rkO1, rvO0, rvO1, rkE0, rkE1, rvE0, rvE1;
    {
        const bf16_t* kp = ksrc + (size_t)64 * LDK;
        rkO0 = *(const bf16x8*)(kp);
        rkO1 = *(const bf16x8*)(kp + 8);
        const bf16_t* vp = vsrc + 64;
        rvO0 = *(const bf16x8*)(vp);
        rvO1 = *(const bf16x8*)(vp + 8);
    }

    float lsA[4] = {}, lsB[4] = {};
    floatx4 oaccA[4] = {}, oaccB[4] = {};
    unsigned int* PLw = &Pl[w][0];
    const float NEG12L2E = -17.3123405f;        // -12 * log2(e)
    bf16x8 pfA0, pfA1, pfB0, pfB1;

// per-iter compute body: QK -> softmax -> P-trip (reads from Kt[CUR]).
#define ATTN_QKSM(CUR)                                                        \
    {                                                                         \
        const bf16_t* Kl = &Kt[CUR][0];                                       \
        floatx4 sA[4], sB[4];                                                 \
        _Pragma("unroll")                                                     \
        for (int kb = 0; kb < 4; ++kb) {                                      \
            bf16x8 k0 = *(const bf16x8*)(&Kl[(kb * 16 + n16) * 72 + g * 8]);  \
            bf16x8 k1 = *(const bf16x8*)(&Kl[(kb * 16 + n16) * 72 + 32 + g * 8]); \
            sA[kb] = floatx4{NEG12L2E, NEG12L2E, NEG12L2E, NEG12L2E};         \
            sA[kb] = MFMA16(k0, qa0, sA[kb]);                                 \
            sA[kb] = MFMA16(k1, qa1, sA[kb]);                                 \
            sB[kb] = floatx4{NEG12L2E, NEG12L2E, NEG12L2E, NEG12L2E};         \
            sB[kb] = MFMA16(k0, qb0, sB[kb]);                                 \
            sB[kb] = MFMA16(k1, qb1, sB[kb]);                                 \
        }                                                                     \
        _Pragma("unroll")                                                     \
        for (int kb = 0; kb < 4; ++kb)                                        \
            _Pragma("unroll")                                                 \
            for (int r = 0; r < 4; ++r) {                                     \
                float eA = exp2f(sA[kb][r]);                                  \
                sA[kb][r] = eA; lsA[kb] += eA;                                \
                float eB = exp2f(sB[kb][r]);                                  \
                sB[kb][r] = eB; lsB[kb] += eB;                                \
            }                                                                 \
        _Pragma("unroll")                                                     \
        for (int kb = 0; kb < 4; ++kb) {                                      \
            uint2 prA, prB;                                                   \
            prA.x = pack2(sA[kb][0], sA[kb][1]);                              \
            prA.y = pack2(sA[kb][2], sA[kb][3]);                              \
            *(uint2*)&PLw[n16 * 68 + kb * 8 + g * 2] = prA;                   \
            prB.x = pack2(sB[kb][0], sB[kb][1]);                              \
            prB.y = pack2(sB[kb][2], sB[kb][3]);                              \
            *(uint2*)&PLw[n16 * 68 + 32 + kb * 8 + g * 2] = prB;              \
        }                                                                     \
        uint4 uA0 = *(const uint4*)&PLw[n16 * 68 + g * 4];                    \
        uint4 uA1 = *(const uint4*)&PLw[n16 * 68 + 16 + g * 4];               \
        uint4 uB0 = *(const uint4*)&PLw[n16 * 68 + 32 + g * 4];               \
        uint4 uB1 = *(const uint4*)&PLw[n16 * 68 + 48 + g * 4];               \
        pfA0 = __builtin_bit_cast(bf16x8, uA0);                               \
        pfA1 = __builtin_bit_cast(bf16x8, uA1);                               \
        pfB0 = __builtin_bit_cast(bf16x8, uB0);                               \
        pfB1 = __builtin_bit_cast(bf16x8, uB1);                               \
    }

#define ATTN_PV(CUR)                                                          \
    {                                                                         \
        const bf16_t* Vl = &Vl2[CUR][0];                                      \
        _Pragma("unroll")                                                     \
        for (int dt = 0; dt < 4; ++dt) {                                      \
            bf16x8 v0 = *(const bf16x8*)(&Vl[(dt * 16 + n16) * 72 + g * 8]);  \
            bf16x8 v1 = *(const bf16x8*)(&Vl[(dt * 16 + n16) * 72 + 32 + g * 8]); \
            oaccA[dt] = MFMA16(v0, pfA0, oaccA[dt]);                          \
            oaccA[dt] = MFMA16(v1, pfA1, oaccA[dt]);                          \
            oaccB[dt] = MFMA16(v0, pfB0, oaccB[dt]);                          \
            oaccB[dt] = MFMA16(v1, pfB1, oaccB[dt]);                          \
        }                                                                     \
    }

    for (int ih = 0; ih < 8; ++ih) {
        int itE = ih * 2;                 // even iter: consume LDS[0]
        int itO = itE + 1;                // odd iter:  consume LDS[1]
        // ======== even iter ========
        __syncthreads();
        if (itE < 14) {                   // issue loads for tile itE+2 (even)
            const bf16_t* kp = ksrc + (size_t)(itE + 2) * 64 * LDK;
            rkE0 = *(const bf16x8*)(kp);
            rkE1 = *(const bf16x8*)(kp + 8);
            const bf16_t* vp = vsrc + (itE + 2) * 64;
            rvE0 = *(const bf16x8*)(vp);
            rvE1 = *(const bf16x8*)(vp + 8);
        }
        ATTN_QKSM(0)
        {   // stage tile itE+1 (odd, loaded a full iter ago) -> LDS[1]
            bf16_t* kd = &Kt[1][srow * 72 + scol];
            bf16_t* vd = &Vl2[1][srow * 72 + scol];
            *(bf16x8*)kd = rkO0; *(bf16x8*)(kd + 8) = rkO1;
            *(bf16x8*)vd = rvO0; *(bf16x8*)(vd + 8) = rvO1;
        }
        ATTN_PV(0)
        // ======== odd iter ========
        __syncthreads();
        if (itO < 14) {                   // issue loads for tile itO+2 (odd)
            const bf16_t* kp = ksrc + (size_t)(itO + 2) * 64 * LDK;
            rkO0 = *(const bf16x8*)(kp);
            rkO1 = *(const bf16x8*)(kp + 8);
            const bf16_t* vp = vsrc + (itO + 2) * 64;
            rvO0 = *(const bf16x8*)(vp);
            rvO1 = *(const bf16x8*)(vp + 8);
        }
        ATTN_QKSM(1)
        if (itO < 15) {                   // stage tile itO+1 (even) -> LDS[0]
            bf16_t* kd = &Kt[0][srow * 72 + scol];
            bf16_t* vd = &Vl2[0][srow * 72 + scol];
            *(bf16x8*)kd = rkE0; *(bf16x8*)(kd + 8) = rkE1;
            *(bf16x8*)vd = rvE0; *(bf16x8*)(vd + 8) = rvE1;
        }
        ATTN_PV(1)
    }
#undef ATTN_QKSM
#undef ATTN_PV

    // ---- l reductions (once) + epilogue for both halves ----
    float lA = (lsA[0] + lsA[1]) + (lsA[2] + lsA[3]);
    lA += __shfl_xor(lA, 16);
    lA += __shfl_xor(lA, 32);
    float lB = (lsB[0] + lsB[1]) + (lsB[2] + lsB[3]);
    lB += __shfl_xor(lB, 16);
    lB += __shfl_xor(lB, 32);
    float rlA = 1.0f / lA, rlB = 1.0f / lB;
    size_t orowA = ((size_t)b * S_LEN + qA) * EMBED + h * HD;
    size_t orowB = orowA + (size_t)16 * EMBED;
#pragma unroll
    for (int dt = 0; dt < 4; ++dt) {
        uint2 prA, prB;
        prA.x = pack2(oaccA[dt][0] * rlA, oaccA[dt][1] * rlA);
        prA.y = pack2(oaccA[dt][2] * rlA, oaccA[dt][3] * rlA);
        *(uint2*)(o + orowA + dt * 16 + g * 4) = prA;
        prB.x = pack2(oaccB[dt][0] * rlB, oaccB[dt][1] * rlB);
        prB.y = pack2(oaccB[dt][2] * rlB, oaccB[dt][3] * rlB);
        *(uint2*)(o + orowB + dt * 16 + g * 4) = prB;
    }
}

extern "C" void kernel_launch(void* const* d_in, const int* in_sizes, int n_in,
                              void* d_out, int out_size, void* d_ws, size_t ws_size,
                              hipStream_t stream) {
    const float* x     = (const float*)d_in[0];
    const float* Wq    = (const float*)d_in[1];
    const float* bq    = (const float*)d_in[2];
    const float* Wk    = (const float*)d_in[3];
    const float* bk    = (const float*)d_in[4];
    const float* Wv    = (const float*)d_in[5];
    const float* bv    = (const float*)d_in[6];
    const float* Wo    = (const float*)d_in[7];
    const float* bo    = (const float*)d_in[8];
    const float* gamma = (const float*)d_in[9];
    const float* beta  = (const float*)d_in[10];
    float* out = (float*)d_out;

    char* ws = (char*)d_ws;                        // ~27.8 MB used
    bf16_t* xn    = (bf16_t*)ws;                   // [0,8M); reused as attn-out
    bf16_t* qkb   = (bf16_t*)(ws + 8388608);       // packed QK [8192][1056] (17.3 MB)
    bf16_t* wqkv  = (bf16_t*)(ws + 25690112);      // 1.5 MB packed [1536][512]
    bf16_t* wo    = (bf16_t*)(ws + 27262976);      // 512 KB
    bf16_t* ab    = xn;

    // vtb (8.9 MB) lives in d_out: dead before wsgemm_out writes out
    bf16_t* vtb = (bf16_t*)d_out;

    ln_cvt_kernel<<<dim3(1024), 256, 0, stream>>>(x, gamma, beta, xn,
                                                  Wq, Wk, Wv, Wo,
                                                  wqkv, wqkv + 262144,
                                                  wqkv + 524288, wo);
    gemm_kernel<<<dim3(64, 12), 256, 0, stream>>>(xn, wqkv, bq, bk, bv, qkb, vtb);
    attn_kernel<<<dim3(512), 256, 0, stream>>>(qkb, vtb, ab);
    wsgemm_out_kernel<<<dim3(16, 4, 8), 256, 0, stream>>>(wo, ab, bo, x, out);
}